// Round 9
// baseline (169.031 us; speedup 1.0000x reference)
//
#include <hip/hip_runtime.h>

// Adaptive separable conv (SepConv): out[b,c,y,x] = sum_i sum_j inp[b,c,y+i,x+j]*v[b,i,y,x]*h[b,j,y,x]
// B=2,C=3,H=W=256,K=51. fp32 in/out. No MFMA path (per-pixel weights; no fp32 MFMA on CDNA4).
//
// R9: split h across LDS + VMEM pipes. R8's counted-vmcnt was neutral -> barrier drain was
// not the stall; the LDS pipe is (h reads = 52% of ~2600 wave-b128/block, 4x wave-redundant).
// Now: per 4-tap chunk, taps {0,1} via LDS DMA (4KB chunks, double-buffered, __syncthreads);
// taps {2,3} read directly from global into registers (hr[4]), prefetched one chunk ahead
// in-place (consume jj=2,3 first, then overwrite with next chunk's loads). This halves
// h LDS reads AND staging, moves ~650MB to the idle VMEM/L2 pipe (12 TB/s vs 34.5 ceiling),
// and shrinks LDS to 34.9KB -> 4 blocks/CU = 16 waves/CU (if VGPR<=128).
// Keeps: R=8, TILE 64x8, 3-slot zero-mov windows, h row-rotation LDS layout (pre-permuted
// DMA source), 1.25 ops/MAC, unroll-1, launch_bounds(256,1), NS=4 i-split (4/3/3/3).

namespace {
constexpr int KK = 51;
constexpr int NB = 2;
constexpr int NC = 3;
constexpr int HH = 256;
constexpr int WW = 256;
constexpr int IN_H = HH + KK - 1;   // 306
constexpr int IN_W = WW + KK - 1;   // 306

constexpr int TILE_W = 64;          // output cols per block
constexpr int TILE_H = 8;           // output rows per block
constexpr int NTX = 8;              // threads along x (each covers R=8 outputs)
constexpr int R = 8;
constexpr int NTY = 8;
constexpr int NS = 4;               // i-tap split (one block-range per wave)
constexpr int NTHREADS = NTX * NTY * NS;   // 256
constexpr int HALO_W = TILE_W + KK - 1;    // 114
constexpr int LDS_W = 116;          // 114 valid + 2 slack
constexpr int LDS_H = TILE_H + KK - 1;     // 58
constexpr int KSTRIDE = HH * WW;    // per-tap stride in v/h (65536)
constexpr int HCH = 2 * TILE_H * TILE_W;   // 1024 floats per h chunk buffer (2 taps)
}

__device__ __forceinline__ float fget(const float4 v, int i) {
  return (i == 0) ? v.x : (i == 1) ? v.y : (i == 2) ? v.z : v.w;
}

// One j-tap: t = sum_ib v[ib]*w[ib], acc += h*t. P = window phase, JJ = j within chunk.
template <int P, int JJ>
__device__ __forceinline__ void fma_jtap(const float4 (&v4)[4][2], const float4 (&w4)[4][3],
                                         const float4 ha, const float4 hb, float (&acc)[R]) {
#pragma unroll
  for (int rx = 0; rx < R; ++rx) {
    const int k  = rx + JJ;            // logical window index 0..10
    const int sl = (P + k / 4) % 3;    // physical slot
    const int cp = k & 3;
    const int vh = rx >> 2, vc = rx & 3;
    float tv = fget(v4[0][vh], vc) * fget(w4[0][sl], cp);
    tv = fmaf(fget(v4[1][vh], vc), fget(w4[1][sl], cp), tv);
    tv = fmaf(fget(v4[2][vh], vc), fget(w4[2][sl], cp), tv);
    tv = fmaf(fget(v4[3][vh], vc), fget(w4[3][sl], cp), tv);
    const float hv = (rx < 4) ? fget(ha, vc) : fget(hb, vc);
    acc[rx] = fmaf(hv, tv, acc[rx]);
  }
}

// Full chunk (4 j-taps) at phase P.
// jj=2,3 consume hr (prefetched last chunk); then hr is overwritten in place with the NEXT
// chunk's taps (j2n/j3n, global); jj=0,1 come from the LDS h buffer; finally refill window
// slot P from the inp tile.
template <int P>
__device__ __forceinline__ void full_chunk(const float4 (&v4)[4][2], float4 (&w4)[4][3],
                                           const int (&woff)[4], int wcol,
                                           const float* hb, int off0, int off1,
                                           float4 (&hr)[4], int j2n, int j3n,
                                           const float* hbase,
                                           float (&acc)[R], const float* smem) {
  fma_jtap<P, 2>(v4, w4, hr[0], hr[1], acc);
  fma_jtap<P, 3>(v4, w4, hr[2], hr[3], acc);
  // In-place prefetch of next chunk's taps {2,3} (WAR on hr is safe: reads already issued).
  hr[0] = *reinterpret_cast<const float4*>(hbase + (size_t)j2n * KSTRIDE);
  hr[1] = *reinterpret_cast<const float4*>(hbase + (size_t)j2n * KSTRIDE + 4);
  hr[2] = *reinterpret_cast<const float4*>(hbase + (size_t)j3n * KSTRIDE);
  hr[3] = *reinterpret_cast<const float4*>(hbase + (size_t)j3n * KSTRIDE + 4);
  const float4 h0a = *reinterpret_cast<const float4*>(hb + off0);
  const float4 h0b = *reinterpret_cast<const float4*>(hb + off1);
  const float4 h1a = *reinterpret_cast<const float4*>(hb + 512 + off0);
  const float4 h1b = *reinterpret_cast<const float4*>(hb + 512 + off1);
  fma_jtap<P, 0>(v4, w4, h0a, h0b, acc);
  fma_jtap<P, 1>(v4, w4, h1a, h1b, acc);
#pragma unroll
  for (int ib = 0; ib < 4; ++ib)
    w4[ib][P] = *reinterpret_cast<const float4*>(&smem[woff[ib] + wcol]);
}

__global__ __launch_bounds__(NTHREADS, 1)
void sepconv_kernel(
    const float* __restrict__ inp,
    const float* __restrict__ vert,
    const float* __restrict__ horiz,
    float* __restrict__ out)
{
  __shared__ float lds[LDS_H * LDS_W];   // 26,912 B (inp tile; reused for reduction)
  __shared__ float hbuf[2 * HCH];        // 8,192 B (h taps {0,1} double buffer)

  const int tid = threadIdx.x;
  const int tx  = tid & (NTX - 1);
  const int ty  = (tid >> 3) & (NTY - 1);
  const int s   = tid >> 6;                    // wave id: 0..3 (wave-uniform)

  const int x0 = blockIdx.x * TILE_W;
  const int y0 = blockIdx.y * TILE_H;
  const int bc = blockIdx.z;                   // 0..5
  const int b  = bc / NC;
  const int c  = bc % NC;

  // ---- Stage input tile: 1ch x 58 rows x 114 cols (float2). Cols 114-115 untouched.
  {
    const float* src = inp + (((size_t)(b * NC + c)) * IN_H + y0) * IN_W + x0;
    constexpr int total2 = LDS_H * (HALO_W / 2);   // 58*57 = 3306
    for (int e = tid; e < total2; e += NTHREADS) {
      const int col2 = e % (HALO_W / 2);
      const int r    = e / (HALO_W / 2);
      const float2 v = *reinterpret_cast<const float2*>(src + (size_t)r * IN_W + col2 * 2);
      float* dst = &lds[r * LDS_W + col2 * 2];
      dst[0] = v.x; dst[1] = v.y;
    }
  }

  // ---- h DMA mapping (1 float4/thread/chunk). Physical float4 slot p = tid:
  // jj=p>>7 (0..1), row=(p&127)>>4, c4=p&15; slot holds global quad q=(c4-row)&15.
  const float* hblk = horiz + (((size_t)b * KK) * HH + y0) * WW + x0;
  const int jj_  = tid >> 7;
  const int rem  = tid & 127;
  const int hrow = rem >> 4;
  const int c4_  = rem & 15;
  const int q_   = (c4_ - hrow) & 15;
  const int goff = hrow * WW + q_ * 4;
  const int ldso = (tid & ~63) * 4;            // wave-uniform DMA dest base (floats)
  auto stage = [&](int cc, int bufn) {
    const int j = 4 * cc + jj_;                // <= 49, always valid
    const float* g = hblk + (size_t)j * KSTRIDE + goff;
    float* l = &hbuf[bufn * HCH + ldso];
    __builtin_amdgcn_global_load_lds((const __attribute__((address_space(1))) void*)g,
                                     (__attribute__((address_space(3))) void*)l, 16, 0, 0);
  };

  const int lx = tx * R;                 // local LDS col base (32B aligned)
  const int xg = x0 + lx;
  const int yg = y0 + ty;
  const float* hbase = horiz + (((size_t)b * KK) * HH + yg) * WW + xg;

  // Prologue: chunk-0 taps {0,1} -> DMA buf0; chunk-0 taps {2,3} -> registers.
  stage(0, 0);
  float4 hr[4];
  hr[0] = *reinterpret_cast<const float4*>(hbase + (size_t)2 * KSTRIDE);
  hr[1] = *reinterpret_cast<const float4*>(hbase + (size_t)2 * KSTRIDE + 4);
  hr[2] = *reinterpret_cast<const float4*>(hbase + (size_t)3 * KSTRIDE);
  hr[3] = *reinterpret_cast<const float4*>(hbase + (size_t)3 * KSTRIDE + 4);
  __syncthreads();      // drains inp staging + chunk-0 DMA (+ hr loads)
  int buf = 0;

  // Rotated h read offsets (invariant): row ty, logical quads 2tx, 2tx+1.
  const int off0 = ty * 64 + ((2 * tx + ty) & 15) * 4;
  const int off1 = ty * 64 + ((2 * tx + 1 + ty) & 15) * 4;

  float acc[R];
#pragma unroll
  for (int rx = 0; rx < R; ++rx) acc[rx] = 0.f;

  // Deal 13 BI=4 tap-blocks (52 virtual taps; tap 51 masked) to 4 waves: 4/3/3/3.
  const int blk0 = (s == 0) ? 0 : (3 * s + 1);   // 0,4,7,10
  const int nblk = (s == 0) ? 4 : 3;             // inactive only at t=3

  const float* vbase = vert + (((size_t)b * KK) * HH + yg) * WW + xg;

#pragma unroll 1
  for (int t = 0; t < 4; ++t) {          // uniform trip count for ALL waves (barriers!)
    const bool act = (t < nblk);
    float4 v4[4][2];
    float4 w4[4][3];
    int    woff[4];
    if (act) {
      const int ibase = (blk0 + t) * 4;
#pragma unroll
      for (int ib = 0; ib < 4; ++ib) {
        const int iv = ibase + ib;                 // <= 51
        const int ic = (iv <= 50) ? iv : 50;
        float4 va = *reinterpret_cast<const float4*>(vbase + (size_t)ic * KSTRIDE);
        float4 vb = *reinterpret_cast<const float4*>(vbase + (size_t)ic * KSTRIDE + 4);
        if (iv > 50) { va = make_float4(0.f, 0.f, 0.f, 0.f); vb = va; }
        v4[ib][0] = va; v4[ib][1] = vb;
        woff[ib] = (ty + ic) * LDS_W;              // row <= 57
        const float4* p = reinterpret_cast<const float4*>(&lds[woff[ib] + lx]);
        w4[ib][0] = p[0]; w4[ib][1] = p[1]; w4[ib][2] = p[2];
      }
    }

#pragma unroll 1
    for (int g = 0; g < 4; ++g) {        // 12 full chunks (cc = 3g..3g+2) + epilogue below
      const int base = lx + 12 * g + 12;
      const int cc = 3 * g;
      stage(cc + 1, buf ^ 1);
      if (act) full_chunk<0>(v4, w4, woff, base + 0, hbuf + buf * HCH, off0, off1,
                             hr, 4 * (cc + 1) + 2, 4 * (cc + 1) + 3, hbase, acc, lds);
      __syncthreads(); buf ^= 1;
      stage(cc + 2, buf ^ 1);
      if (act) full_chunk<1>(v4, w4, woff, base + 4, hbuf + buf * HCH, off0, off1,
                             hr, 4 * (cc + 2) + 2, 4 * (cc + 2) + 3, hbase, acc, lds);
      __syncthreads(); buf ^= 1;
      stage(cc + 3, buf ^ 1);            // g=3 -> cc=12 (epilogue chunk taps 48,49)
      {
        const int ccn = cc + 3;
        const int j2n = 4 * ccn + 2;               // <= 50 (cc=12 -> 50)
        const int j3n = (4 * ccn + 3 <= 50) ? 4 * ccn + 3 : 50;   // cc=12: clamp (unused)
        if (act) full_chunk<2>(v4, w4, woff, base + 8, hbuf + buf * HCH, off0, off1,
                               hr, j2n, j3n, hbase, acc, lds);
      }
      __syncthreads(); buf ^= 1;
    }

    // Epilogue chunk (cc=12): taps 48,49 from LDS; tap 50 = hr[0],hr[1]; tap 51 skipped.
    stage(0, buf ^ 1);                   // chunk 0 of next tap-block (dead at t=3, harmless)
    if (act) {
      fma_jtap<0, 2>(v4, w4, hr[0], hr[1], acc);
      // Prefetch chunk 0 taps {2,3} for the next tap-block.
      hr[0] = *reinterpret_cast<const float4*>(hbase + (size_t)2 * KSTRIDE);
      hr[1] = *reinterpret_cast<const float4*>(hbase + (size_t)2 * KSTRIDE + 4);
      hr[2] = *reinterpret_cast<const float4*>(hbase + (size_t)3 * KSTRIDE);
      hr[3] = *reinterpret_cast<const float4*>(hbase + (size_t)3 * KSTRIDE + 4);
      const float* hb = hbuf + buf * HCH;
      const float4 e0a = *reinterpret_cast<const float4*>(hb + off0);
      const float4 e0b = *reinterpret_cast<const float4*>(hb + off1);
      const float4 e1a = *reinterpret_cast<const float4*>(hb + 512 + off0);
      const float4 e1b = *reinterpret_cast<const float4*>(hb + 512 + off1);
      fma_jtap<0, 0>(v4, w4, e0a, e0b, acc);
      fma_jtap<0, 1>(v4, w4, e1a, e1b, acc);
    }
    __syncthreads(); buf ^= 1;
  }

  // ---- Reduce the 4 i-split partials (waves 1..3 -> LDS inp region, wave 0 adds & stores)
  if (s > 0) {
    float* p = &lds[((s - 1) * 64 + ty * NTX + tx) * R];
#pragma unroll
    for (int rx = 0; rx < R; ++rx) p[rx] = acc[rx];
  }
  __syncthreads();
  if (s == 0) {
#pragma unroll
    for (int g = 0; g < 3; ++g) {
      const float* p = &lds[(g * 64 + ty * NTX + tx) * R];
#pragma unroll
      for (int rx = 0; rx < R; ++rx) acc[rx] += p[rx];
    }
    float* o = out + (((size_t)(b * NC + c)) * HH + yg) * WW + xg;
    *reinterpret_cast<float4*>(o)     = make_float4(acc[0], acc[1], acc[2], acc[3]);
    *reinterpret_cast<float4*>(o + 4) = make_float4(acc[4], acc[5], acc[6], acc[7]);
  }
}

extern "C" void kernel_launch(void* const* d_in, const int* in_sizes, int n_in,
                              void* d_out, int out_size, void* d_ws, size_t ws_size,
                              hipStream_t stream) {
  const float* inp   = (const float*)d_in[0];
  const float* vert  = (const float*)d_in[1];
  const float* horiz = (const float*)d_in[2];
  float* out = (float*)d_out;

  dim3 grid(WW / TILE_W, HH / TILE_H, NB * NC);   // 4 x 32 x 6 = 768 blocks x 256 threads
  sepconv_kernel<<<grid, NTHREADS, 0, stream>>>(inp, vert, horiz, out);
}

// Round 10
// 151.079 us; speedup vs baseline: 1.1188x; 1.1188x over previous
//
#include <hip/hip_runtime.h>

// Adaptive separable conv (SepConv): out[b,c,y,x] = sum_i sum_j inp[b,c,y+i,x+j]*v[b,i,y,x]*h[b,j,y,x]
// B=2,C=3,H=W=256,K=51. fp32 in/out. No MFMA path (per-pixel weights; no fp32 MFMA on CDNA4).
//
// R10: halve the barrier rate. R8 re-analysis: its vmcnt(2) was a no-op (only 2 vmem
// outstanding) => R8 ran with NO DMA wait and was neutral => barrier DMA-drain costs ~0.
// R7's 37us gap (73 wall vs ~36 LDS-floor) is the 52 barrier-steps phase-locking all 12
// resident waves: post-barrier LDS bursts (12 waves x 12 b128) serialize while VALU idles,
// then LDS idles during FMA phase (~50% LDS-pipe util). Fix: stage 2-chunk units (16KB),
// one __syncthreads per unit -> 26 steps; each step ~2x compute span so waves drift and
// spread the bursts. Cost: h buffers 2x16KB -> LDS 59.7KB -> 2 blocks/CU (8 waves vs 12).
// Clean A/B: burst theory -> 58-64us; occupancy theory -> 85-95us.
// Keeps R7: R=8, TILE 64x8, 3-slot zero-mov windows, h row-rotation DMA layout,
// 1.25 ops/MAC, NS=4 i-split 4/3/3/3, plain __syncthreads, launch_bounds(256,1).

namespace {
constexpr int KK = 51;
constexpr int NB = 2;
constexpr int NC = 3;
constexpr int HH = 256;
constexpr int WW = 256;
constexpr int IN_H = HH + KK - 1;   // 306
constexpr int IN_W = WW + KK - 1;   // 306

constexpr int TILE_W = 64;          // output cols per block
constexpr int TILE_H = 8;           // output rows per block
constexpr int NTX = 8;              // threads along x (each covers R=8 outputs)
constexpr int R = 8;
constexpr int NTY = 8;
constexpr int NS = 4;               // i-tap split (one block-range per wave)
constexpr int NTHREADS = NTX * NTY * NS;   // 256
constexpr int HALO_W = TILE_W + KK - 1;    // 114
constexpr int LDS_W = 116;          // 114 valid + 2 slack
constexpr int LDS_H = TILE_H + KK - 1;     // 58
constexpr int KSTRIDE = HH * WW;    // per-tap stride in v/h (65536)
constexpr int HCH  = 4 * TILE_H * TILE_W;  // 2048 floats per 4-tap chunk
constexpr int UNIT = 2 * HCH;              // 4096 floats per 2-chunk stage unit (16KB)
}

__device__ __forceinline__ float fget(const float4 v, int i) {
  return (i == 0) ? v.x : (i == 1) ? v.y : (i == 2) ? v.z : v.w;
}

// One j-tap: t = sum_ib v[ib]*w[ib], acc += h*t. P = window phase, JJ = j within chunk.
template <int P, int JJ>
__device__ __forceinline__ void fma_jtap(const float4 (&v4)[4][2], const float4 (&w4)[4][3],
                                         const float4 ha, const float4 hb, float (&acc)[R]) {
#pragma unroll
  for (int rx = 0; rx < R; ++rx) {
    const int k  = rx + JJ;            // logical window index 0..10
    const int sl = (P + k / 4) % 3;    // physical slot
    const int cp = k & 3;
    const int vh = rx >> 2, vc = rx & 3;
    float tv = fget(v4[0][vh], vc) * fget(w4[0][sl], cp);
    tv = fmaf(fget(v4[1][vh], vc), fget(w4[1][sl], cp), tv);
    tv = fmaf(fget(v4[2][vh], vc), fget(w4[2][sl], cp), tv);
    tv = fmaf(fget(v4[3][vh], vc), fget(w4[3][sl], cp), tv);
    const float hv = (rx < 4) ? fget(ha, vc) : fget(hb, vc);
    acc[rx] = fmaf(hv, tv, acc[rx]);
  }
}

// Full chunk (4 j-taps) at phase P; h from LDS region hb (one 2048-float chunk);
// then refill the vacated window slot P from the inp tile.
template <int P>
__device__ __forceinline__ void full_chunk(const float4 (&v4)[4][2], float4 (&w4)[4][3],
                                           const int (&woff)[4], int wcol,
                                           const float* hb, int off0, int off1,
                                           float (&acc)[R], const float* smem) {
  const float4 h0a = *reinterpret_cast<const float4*>(hb + off0);
  const float4 h0b = *reinterpret_cast<const float4*>(hb + off1);
  const float4 h1a = *reinterpret_cast<const float4*>(hb + 512 + off0);
  const float4 h1b = *reinterpret_cast<const float4*>(hb + 512 + off1);
  fma_jtap<P, 0>(v4, w4, h0a, h0b, acc);
  const float4 h2a = *reinterpret_cast<const float4*>(hb + 1024 + off0);
  const float4 h2b = *reinterpret_cast<const float4*>(hb + 1024 + off1);
  fma_jtap<P, 1>(v4, w4, h1a, h1b, acc);
  const float4 h3a = *reinterpret_cast<const float4*>(hb + 1536 + off0);
  const float4 h3b = *reinterpret_cast<const float4*>(hb + 1536 + off1);
  fma_jtap<P, 2>(v4, w4, h2a, h2b, acc);
  fma_jtap<P, 3>(v4, w4, h3a, h3b, acc);
#pragma unroll
  for (int ib = 0; ib < 4; ++ib)
    w4[ib][P] = *reinterpret_cast<const float4*>(&smem[woff[ib] + wcol]);
}

__global__ __launch_bounds__(NTHREADS, 1)
void sepconv_kernel(
    const float* __restrict__ inp,
    const float* __restrict__ vert,
    const float* __restrict__ horiz,
    float* __restrict__ out)
{
  __shared__ float lds[LDS_H * LDS_W];   // 26,912 B (inp tile; reused for reduction)
  __shared__ float hbuf[2 * UNIT];       // 32,768 B (two 2-chunk h units)

  const int tid = threadIdx.x;
  const int tx  = tid & (NTX - 1);
  const int ty  = (tid >> 3) & (NTY - 1);
  const int s   = tid >> 6;                    // wave id: 0..3 (wave-uniform)

  const int x0 = blockIdx.x * TILE_W;
  const int y0 = blockIdx.y * TILE_H;
  const int bc = blockIdx.z;                   // 0..5
  const int b  = bc / NC;
  const int c  = bc % NC;

  // ---- Stage input tile: 1ch x 58 rows x 114 cols (float2). Cols 114-115 untouched.
  {
    const float* src = inp + (((size_t)(b * NC + c)) * IN_H + y0) * IN_W + x0;
    constexpr int total2 = LDS_H * (HALO_W / 2);   // 58*57 = 3306
    for (int e = tid; e < total2; e += NTHREADS) {
      const int col2 = e % (HALO_W / 2);
      const int r    = e / (HALO_W / 2);
      const float2 v = *reinterpret_cast<const float2*>(src + (size_t)r * IN_W + col2 * 2);
      float* dst = &lds[r * LDS_W + col2 * 2];
      dst[0] = v.x; dst[1] = v.y;
    }
  }

  // ---- h DMA mapping. Unit = 8 taps x 128 float4-slots. Physical slot p = r*256 + tid:
  // tap jj = p>>7 (0..7), row=(p&127)>>4, c4=p&15; slot holds global quad q=(c4-row)&15
  // (per-row rotation so the b128 read hits the 8-touch/bank floor).
  const float* hblk = horiz + (((size_t)b * KK) * HH + y0) * WW + x0;
  int jj_[4], goff_[4], ldso_[4];
#pragma unroll
  for (int r = 0; r < 4; ++r) {
    const int p   = r * 256 + tid;
    const int rem = p & 127;
    const int row = rem >> 4;
    const int c4  = rem & 15;
    const int q   = (c4 - row) & 15;
    jj_[r]   = p >> 7;
    goff_[r] = row * WW + q * 4;
    ldso_[r] = (r * 256 + (tid & ~63)) * 4;    // wave-uniform DMA dest base (floats)
  }
  auto stage_full = [&](int jbase, int bufn) {  // 2 chunks = taps jbase..jbase+7 (<=47)
#pragma unroll
    for (int r = 0; r < 4; ++r) {
      const float* g = hblk + (size_t)(jbase + jj_[r]) * KSTRIDE + goff_[r];
      float* l = &hbuf[bufn * UNIT + ldso_[r]];
      __builtin_amdgcn_global_load_lds((const __attribute__((address_space(1))) void*)g,
                                       (__attribute__((address_space(3))) void*)l, 16, 0, 0);
    }
  };
  auto stage_half = [&](int bufn) {             // chunk 12 = taps 48..51 (51 clamped, unread)
#pragma unroll
    for (int r = 0; r < 2; ++r) {
      const int j  = 48 + jj_[r];
      const int jc = (j <= 50) ? j : 50;
      const float* g = hblk + (size_t)jc * KSTRIDE + goff_[r];
      float* l = &hbuf[bufn * UNIT + ldso_[r]];
      __builtin_amdgcn_global_load_lds((const __attribute__((address_space(1))) void*)g,
                                       (__attribute__((address_space(3))) void*)l, 16, 0, 0);
    }
  };

  // Prologue: unit 0 (chunks 0,1) -> buf0. Sync drains inp staging + DMA.
  stage_full(0, 0);
  __syncthreads();
  int buf = 0;
  int un  = 1;   // next unit (0..5 full, 6 = half), cycles per round

  auto stage_next = [&]() {
    if (un < 6) stage_full(8 * un, buf ^ 1);
    else        stage_half(buf ^ 1);
    un = (un == 6) ? 0 : un + 1;
  };

  const int lx = tx * R;                 // local LDS col base (32B aligned)
  const int xg = x0 + lx;
  const int yg = y0 + ty;

  // Rotated h read offsets (invariant): row ty, logical quads 2tx, 2tx+1.
  const int off0 = ty * 64 + ((2 * tx + ty) & 15) * 4;
  const int off1 = ty * 64 + ((2 * tx + 1 + ty) & 15) * 4;

  float acc[R];
#pragma unroll
  for (int rx = 0; rx < R; ++rx) acc[rx] = 0.f;

  // Deal 13 BI=4 tap-blocks (52 virtual taps; tap 51 masked) to 4 waves: 4/3/3/3.
  const int blk0 = (s == 0) ? 0 : (3 * s + 1);   // 0,4,7,10
  const int nblk = (s == 0) ? 4 : 3;

  const float* vbase = vert + (((size_t)b * KK) * HH + yg) * WW + xg;

#pragma unroll 1
  for (int t = 0; t < 4; ++t) {          // uniform trip count for ALL waves (barriers!)
    const bool act = (t < nblk);
    float4 v4[4][2];
    float4 w4[4][3];
    int    woff[4];
    if (act) {
      const int ibase = (blk0 + t) * 4;
#pragma unroll
      for (int ib = 0; ib < 4; ++ib) {
        const int iv = ibase + ib;                 // <= 51
        const int ic = (iv <= 50) ? iv : 50;
        float4 va = *reinterpret_cast<const float4*>(vbase + (size_t)ic * KSTRIDE);
        float4 vb = *reinterpret_cast<const float4*>(vbase + (size_t)ic * KSTRIDE + 4);
        if (iv > 50) { va = make_float4(0.f, 0.f, 0.f, 0.f); vb = va; }
        v4[ib][0] = va; v4[ib][1] = vb;
        woff[ib] = (ty + ic) * LDS_W;              // row <= 57
        const float4* p = reinterpret_cast<const float4*>(&lds[woff[ib] + lx]);
        w4[ib][0] = p[0]; w4[ib][1] = p[1]; w4[ib][2] = p[2];
      }
    }

    // 6 full steps (2 chunks each, cc = 6h2 + 2k + ci, phase = cc mod 3), then epilogue.
#pragma unroll 1
    for (int h2 = 0; h2 < 2; ++h2) {
      const int cb = lx + 24 * h2 + 12;          // wcol base: lx + 4*(6h2) + 12
      const float* hb0;
      // step A: chunks 6h2+0 (P0), 6h2+1 (P1)
      stage_next();
      hb0 = hbuf + buf * UNIT;
      if (act) {
        full_chunk<0>(v4, w4, woff, cb + 0, hb0,        off0, off1, acc, lds);
        full_chunk<1>(v4, w4, woff, cb + 4, hb0 + HCH,  off0, off1, acc, lds);
      }
      __syncthreads(); buf ^= 1;
      // step B: chunks 6h2+2 (P2), 6h2+3 (P0)
      stage_next();
      hb0 = hbuf + buf * UNIT;
      if (act) {
        full_chunk<2>(v4, w4, woff, cb + 8,  hb0,       off0, off1, acc, lds);
        full_chunk<0>(v4, w4, woff, cb + 12, hb0 + HCH, off0, off1, acc, lds);
      }
      __syncthreads(); buf ^= 1;
      // step C: chunks 6h2+4 (P1), 6h2+5 (P2)
      stage_next();
      hb0 = hbuf + buf * UNIT;
      if (act) {
        full_chunk<1>(v4, w4, woff, cb + 16, hb0,       off0, off1, acc, lds);
        full_chunk<2>(v4, w4, woff, cb + 20, hb0 + HCH, off0, off1, acc, lds);
      }
      __syncthreads(); buf ^= 1;
    }

    // Epilogue step: chunk 12 (phase 0): j = 48,49,50.
    stage_next();                        // next round's unit 0 (dead at t=3, harmless)
    if (act) {
      const float* hb = hbuf + buf * UNIT;
      const float4 e0a = *reinterpret_cast<const float4*>(hb + off0);
      const float4 e0b = *reinterpret_cast<const float4*>(hb + off1);
      const float4 e1a = *reinterpret_cast<const float4*>(hb + 512 + off0);
      const float4 e1b = *reinterpret_cast<const float4*>(hb + 512 + off1);
      const float4 e2a = *reinterpret_cast<const float4*>(hb + 1024 + off0);
      const float4 e2b = *reinterpret_cast<const float4*>(hb + 1024 + off1);
      fma_jtap<0, 0>(v4, w4, e0a, e0b, acc);
      fma_jtap<0, 1>(v4, w4, e1a, e1b, acc);
      fma_jtap<0, 2>(v4, w4, e2a, e2b, acc);
    }
    __syncthreads(); buf ^= 1;
  }

  // ---- Reduce the 4 i-split partials (waves 1..3 -> LDS inp region, wave 0 adds & stores)
  // (the loop's trailing __syncthreads orders all inp-tile reads before the overwrite)
  if (s > 0) {
    float* p = &lds[((s - 1) * 64 + ty * NTX + tx) * R];
#pragma unroll
    for (int rx = 0; rx < R; ++rx) p[rx] = acc[rx];
  }
  __syncthreads();
  if (s == 0) {
#pragma unroll
    for (int g = 0; g < 3; ++g) {
      const float* p = &lds[(g * 64 + ty * NTX + tx) * R];
#pragma unroll
      for (int rx = 0; rx < R; ++rx) acc[rx] += p[rx];
    }
    float* o = out + (((size_t)(b * NC + c)) * HH + yg) * WW + xg;
    *reinterpret_cast<float4*>(o)     = make_float4(acc[0], acc[1], acc[2], acc[3]);
    *reinterpret_cast<float4*>(o + 4) = make_float4(acc[4], acc[5], acc[6], acc[7]);
  }
}

extern "C" void kernel_launch(void* const* d_in, const int* in_sizes, int n_in,
                              void* d_out, int out_size, void* d_ws, size_t ws_size,
                              hipStream_t stream) {
  const float* inp   = (const float*)d_in[0];
  const float* vert  = (const float*)d_in[1];
  const float* horiz = (const float*)d_in[2];
  float* out = (float*)d_out;

  dim3 grid(WW / TILE_W, HH / TILE_H, NB * NC);   // 4 x 32 x 6 = 768 blocks x 256 threads
  sepconv_kernel<<<grid, NTHREADS, 0, stream>>>(inp, vert, horiz, out);
}